// Round 1
// baseline (1566.535 us; speedup 1.0000x reference)
//
#include <hip/hip_runtime.h>
#include <math.h>

#define NN 50000
#define NE 800000
#define NB 64

// ---------------- zero ----------------
__global__ void k_zero(int* __restrict__ p, int n) {
  int i = blockIdx.x * blockDim.x + threadIdx.x;
  if (i < n) p[i] = 0;
}

// ---------------- fused weight precompute ----------------
// wl1e[16][256] = Wn@Wl1 ; wr1e likewise ; wfe1[8][256]=We@We1 ; wfe2[8][64]=We@We2
// bl1e = bn@Wl1 + bl1 ; br1e = bn@Wr1 + br1 ; bfe1 = be@We1 ; bfe2 = be@We2
__global__ void k_fuse(const float* __restrict__ Wn, const float* __restrict__ bn,
                       const float* __restrict__ We, const float* __restrict__ be,
                       const float* __restrict__ Wl1, const float* __restrict__ bl1,
                       const float* __restrict__ Wr1, const float* __restrict__ br1,
                       const float* __restrict__ We1, const float* __restrict__ We2,
                       float* __restrict__ wl1e, float* __restrict__ bl1e,
                       float* __restrict__ wr1e, float* __restrict__ br1e,
                       float* __restrict__ wfe1, float* __restrict__ bfe1,
                       float* __restrict__ wfe2, float* __restrict__ bfe2) {
  int t = blockIdx.x * blockDim.x + threadIdx.x;
  if (t < 4096) {
    int i = t >> 8, j = t & 255; float s = 0.f;
    for (int k = 0; k < 64; k++) s += Wn[i * 64 + k] * Wl1[k * 256 + j];
    wl1e[t] = s;
  } else if (t < 8192) {
    int u = t - 4096; int i = u >> 8, j = u & 255; float s = 0.f;
    for (int k = 0; k < 64; k++) s += Wn[i * 64 + k] * Wr1[k * 256 + j];
    wr1e[u] = s;
  } else if (t < 10240) {
    int u = t - 8192; int i = u >> 8, j = u & 255; float s = 0.f;
    for (int k = 0; k < 64; k++) s += We[i * 64 + k] * We1[k * 256 + j];
    wfe1[u] = s;
  } else if (t < 10752) {
    int u = t - 10240; int i = u >> 6, j = u & 63; float s = 0.f;
    for (int k = 0; k < 64; k++) s += We[i * 64 + k] * We2[k * 64 + j];
    wfe2[u] = s;
  } else if (t < 11008) {
    int j = t - 10752; float s = bl1[j];
    for (int k = 0; k < 64; k++) s += bn[k] * Wl1[k * 256 + j];
    bl1e[j] = s;
  } else if (t < 11264) {
    int j = t - 11008; float s = br1[j];
    for (int k = 0; k < 64; k++) s += bn[k] * Wr1[k * 256 + j];
    br1e[j] = s;
  } else if (t < 11520) {
    int j = t - 11264; float s = 0.f;
    for (int k = 0; k < 64; k++) s += be[k] * We1[k * 256 + j];
    bfe1[j] = s;
  } else if (t < 11584) {
    int j = t - 11520; float s = 0.f;
    for (int k = 0; k < 64; k++) s += be[k] * We2[k * 64 + j];
    bfe2[j] = s;
  }
}

// ---------------- degree + raw edge_attr segment sum (for self-loop mean) ----------------
__global__ void k_deg(const int* __restrict__ dstA, const float* __restrict__ eattr,
                      int* __restrict__ deg, float* __restrict__ sum8) {
  int e = blockIdx.x * blockDim.x + threadIdx.x;
  if (e >= NE) return;
  int d = dstA[e];
  atomicAdd(&deg[d], 1);
#pragma unroll
  for (int k = 0; k < 8; k++) atomicAdd(&sum8[d * 8 + k], eattr[e * 8 + k]);
}

// ---------------- exclusive scan of (deg+1) -> rowptr ----------------
__global__ void k_scan(const int* __restrict__ deg, int* __restrict__ rowptr) {
  __shared__ int sm[1024];
  __shared__ int carry_s;
  if (threadIdx.x == 0) carry_s = 0;
  __syncthreads();
  for (int base = 0; base < NN; base += 1024) {
    int i = base + threadIdx.x;
    int v = (i < NN) ? (deg[i] + 1) : 0;
    sm[threadIdx.x] = v;
    __syncthreads();
    for (int off = 1; off < 1024; off <<= 1) {
      int t = 0;
      if (threadIdx.x >= off) t = sm[threadIdx.x - off];
      __syncthreads();
      sm[threadIdx.x] += t;
      __syncthreads();
    }
    int carry = carry_s;
    if (i < NN) rowptr[i] = carry + sm[threadIdx.x] - v;
    __syncthreads();
    if (threadIdx.x == 1023) carry_s = carry + sm[1023];
    __syncthreads();
  }
  if (threadIdx.x == 0) rowptr[NN] = carry_s;
}

// ---------------- CSR fill (real edges via cursor; self-loop id = NE+n at slot end) ----------------
__global__ void k_csr(const int* __restrict__ dstA, const int* __restrict__ rowptr,
                      const int* __restrict__ deg, int* __restrict__ cursor,
                      int* __restrict__ csr) {
  int t = blockIdx.x * blockDim.x + threadIdx.x;
  if (t < NE) {
    int d = dstA[t];
    int pos = rowptr[d] + atomicAdd(&cursor[d], 1);
    csr[pos] = t;
  } else if (t < NE + NN) {
    int n = t - NE;
    csr[rowptr[n] + deg[n]] = NE + n;
  }
}

// ---------------- xl1/xr1 = x @ wl1e/wr1e + biases  (block = one node, 256 threads) ----------------
__global__ __launch_bounds__(256) void k_lin1(const float* __restrict__ x,
                                              const float* __restrict__ wl, const float* __restrict__ bl,
                                              const float* __restrict__ wr, const float* __restrict__ br,
                                              float* __restrict__ xl, float* __restrict__ xr) {
  __shared__ float xrow[16];
  int node = blockIdx.x;
  int j = threadIdx.x;
  if (threadIdx.x < 16) xrow[threadIdx.x] = x[node * 16 + threadIdx.x];
  __syncthreads();
  float sl = bl[j], sr = br[j];
#pragma unroll
  for (int k = 0; k < 16; k++) {
    float v = xrow[k];
    sl += v * wl[k * 256 + j];
    sr += v * wr[k * 256 + j];
  }
  xl[node * 256 + j] = sl;
  xr[node * 256 + j] = sr;
}

// ---------------- conv1: GATv2 4 heads, online-softmax gather, one wave per node ----------------
__global__ __launch_bounds__(256) void k_conv1(
    const int* __restrict__ srcA, const float* __restrict__ eattr,
    const int* __restrict__ rowptr, const float* __restrict__ sum8,
    const int* __restrict__ csr,
    const float* __restrict__ xl, const float* __restrict__ xrg,
    const float* __restrict__ att1, const float* __restrict__ bias1,
    const float* __restrict__ wfe1, const float* __restrict__ bfe1,
    float* __restrict__ out1) {
  int d = (blockIdx.x * blockDim.x + threadIdx.x) >> 6;
  int lane = threadIdx.x & 63;
  if (d >= NN) return;

  float xr_l[4], att_l[4], bfe_l[4], acc[4], mrun[4], lrun[4];
#pragma unroll
  for (int h = 0; h < 4; h++) {
    xr_l[h] = xrg[d * 256 + h * 64 + lane];
    att_l[h] = att1[h * 64 + lane];
    bfe_l[h] = bfe1[h * 64 + lane];
    acc[h] = 0.f; mrun[h] = -INFINITY; lrun[h] = 0.f;
  }
  int beg = rowptr[d], end = rowptr[d + 1];
  float invdeg = 1.f / fmaxf((float)(end - beg - 1), 1.f);

  for (int idx = beg; idx < end; ++idx) {
    int eid = csr[idx];
    int s;
    float ek[8];
    if (eid < NE) {
      s = srcA[eid];
#pragma unroll
      for (int k = 0; k < 8; k++) ek[k] = eattr[eid * 8 + k];
    } else {
      s = d;
#pragma unroll
      for (int k = 0; k < 8; k++) ek[k] = sum8[d * 8 + k] * invdeg;
    }
#pragma unroll
    for (int h = 0; h < 4; h++) {
      float ep = bfe_l[h];
#pragma unroll
      for (int k = 0; k < 8; k++) ep += ek[k] * wfe1[k * 256 + h * 64 + lane];
      float xls = xl[s * 256 + h * 64 + lane];
      float m = xls + xr_l[h] + ep;
      m = (m > 0.f) ? m : 0.2f * m;
      float part = att_l[h] * m;
#pragma unroll
      for (int o = 32; o >= 1; o >>= 1) part += __shfl_xor(part, o, 64);
      float nm = fmaxf(mrun[h], part);
      float sc = __expf(mrun[h] - nm);
      float p = __expf(part - nm);
      lrun[h] = lrun[h] * sc + p;
      acc[h] = acc[h] * sc + p * xls;
      mrun[h] = nm;
    }
  }
#pragma unroll
  for (int h = 0; h < 4; h++) {
    float o = acc[h] / (lrun[h] + 1e-16f) + bias1[h * 64 + lane];
    out1[d * 256 + h * 64 + lane] = (o > 0.f) ? o : (__expf(o) - 1.f);
  }
}

// ---------------- xl2/xr2 = out1 @ Wl2/Wr2 + biases (4 nodes per block) ----------------
__global__ __launch_bounds__(256) void k_lin2(const float* __restrict__ in,
                                              const float* __restrict__ wl, const float* __restrict__ bl,
                                              const float* __restrict__ wr, const float* __restrict__ br,
                                              float* __restrict__ xl, float* __restrict__ xr) {
  int node = blockIdx.x * 4 + (threadIdx.x >> 6);
  int j = threadIdx.x & 63;
  if (node >= NN) return;
  float sl = bl[j], sr = br[j];
  const float4* row4 = (const float4*)(in + node * 256);
#pragma unroll 4
  for (int k4 = 0; k4 < 64; k4++) {
    float4 v = row4[k4];
    int k = k4 * 4;
    sl += v.x * wl[(k + 0) * 64 + j] + v.y * wl[(k + 1) * 64 + j] +
          v.z * wl[(k + 2) * 64 + j] + v.w * wl[(k + 3) * 64 + j];
    sr += v.x * wr[(k + 0) * 64 + j] + v.y * wr[(k + 1) * 64 + j] +
          v.z * wr[(k + 2) * 64 + j] + v.w * wr[(k + 3) * 64 + j];
  }
  xl[node * 64 + j] = sl;
  xr[node * 64 + j] = sr;
}

// ---------------- conv2: GATv2 1 head ----------------
__global__ __launch_bounds__(256) void k_conv2(
    const int* __restrict__ srcA, const float* __restrict__ eattr,
    const int* __restrict__ rowptr, const float* __restrict__ sum8,
    const int* __restrict__ csr,
    const float* __restrict__ xl, const float* __restrict__ xrg,
    const float* __restrict__ att2, const float* __restrict__ bias2,
    const float* __restrict__ wfe2, const float* __restrict__ bfe2,
    float* __restrict__ out2) {
  int d = (blockIdx.x * blockDim.x + threadIdx.x) >> 6;
  int lane = threadIdx.x & 63;
  if (d >= NN) return;
  float xr_l = xrg[d * 64 + lane];
  float att_l = att2[lane];
  float bfe_l = bfe2[lane];
  float acc = 0.f, mrun = -INFINITY, lrun = 0.f;
  int beg = rowptr[d], end = rowptr[d + 1];
  float invdeg = 1.f / fmaxf((float)(end - beg - 1), 1.f);
  for (int idx = beg; idx < end; ++idx) {
    int eid = csr[idx];
    int s;
    float ek[8];
    if (eid < NE) {
      s = srcA[eid];
#pragma unroll
      for (int k = 0; k < 8; k++) ek[k] = eattr[eid * 8 + k];
    } else {
      s = d;
#pragma unroll
      for (int k = 0; k < 8; k++) ek[k] = sum8[d * 8 + k] * invdeg;
    }
    float ep = bfe_l;
#pragma unroll
    for (int k = 0; k < 8; k++) ep += ek[k] * wfe2[k * 64 + lane];
    float xls = xl[s * 64 + lane];
    float m = xls + xr_l + ep;
    m = (m > 0.f) ? m : 0.2f * m;
    float part = att_l * m;
#pragma unroll
    for (int o = 32; o >= 1; o >>= 1) part += __shfl_xor(part, o, 64);
    float nm = fmaxf(mrun, part);
    float sc = __expf(mrun - nm);
    float p = __expf(part - nm);
    lrun = lrun * sc + p;
    acc = acc * sc + p * xls;
    mrun = nm;
  }
  out2[d * 64 + lane] = acc / (lrun + 1e-16f) + bias2[lane];
}

// ---------------- global mean pool: block per batch segment (batch sorted) ----------------
__device__ __forceinline__ int lowerb(const int* a, int n, int v) {
  int lo = 0, hi = n;
  while (lo < hi) {
    int mid = (lo + hi) >> 1;
    if (a[mid] < v) lo = mid + 1; else hi = mid;
  }
  return lo;
}

__global__ __launch_bounds__(256) void k_pool(const int* __restrict__ batch,
                                              const float* __restrict__ out2,
                                              float* __restrict__ pooled) {
  int b = blockIdx.x;
  int start = lowerb(batch, NN, b);
  int end = lowerb(batch, NN, b + 1);
  int c = threadIdx.x & 63, sub = threadIdx.x >> 6;
  float s = 0.f;
  for (int i = start + sub; i < end; i += 4) s += out2[i * 64 + c];
  __shared__ float sm[256];
  sm[threadIdx.x] = s;
  __syncthreads();
  if (sub == 0) {
    float tot = sm[c] + sm[64 + c] + sm[128 + c] + sm[192 + c];
    float cnt = fmaxf((float)(end - start), 1.f);
    pooled[b * 64 + c] = tot / cnt;
  }
}

// ---------------- decoder: relu(pooled@Wd1+bd1)@Wd2+bd2 -> sigmoid ----------------
__global__ __launch_bounds__(1024) void k_dec(const float* __restrict__ pooled,
                                              const float* __restrict__ Wd1, const float* __restrict__ bd1,
                                              const float* __restrict__ Wd2, const float* __restrict__ bd2,
                                              float* __restrict__ out) {
  __shared__ float hid[64 * 64];
  int t = threadIdx.x;
  for (int i = t; i < 4096; i += 1024) {
    int b = i >> 6, j = i & 63;
    float s = bd1[j];
#pragma unroll 8
    for (int k = 0; k < 64; k++) s += pooled[b * 64 + k] * Wd1[k * 64 + j];
    hid[i] = fmaxf(s, 0.f);
  }
  __syncthreads();
  if (t < 128) {
    int b = t >> 1, o = t & 1;
    float s = bd2[o];
#pragma unroll 8
    for (int k = 0; k < 64; k++) s += hid[b * 64 + k] * Wd2[k * 2 + o];
    out[t] = 1.f / (1.f + __expf(-s));
  }
}

extern "C" void kernel_launch(void* const* d_in, const int* in_sizes, int n_in,
                              void* d_out, int out_size, void* d_ws, size_t ws_size,
                              hipStream_t stream) {
  const float* x     = (const float*)d_in[0];
  const int*   eidx  = (const int*)d_in[1];
  const float* eattr = (const float*)d_in[2];
  const int*   batch = (const int*)d_in[3];
  const float* Wn    = (const float*)d_in[4];
  const float* bn    = (const float*)d_in[5];
  const float* We    = (const float*)d_in[6];
  const float* be    = (const float*)d_in[7];
  const float* Wl1   = (const float*)d_in[8];
  const float* bl1   = (const float*)d_in[9];
  const float* Wr1   = (const float*)d_in[10];
  const float* br1   = (const float*)d_in[11];
  const float* We1   = (const float*)d_in[12];
  const float* att1  = (const float*)d_in[13];
  const float* bias1 = (const float*)d_in[14];
  const float* Wl2   = (const float*)d_in[15];
  const float* bl2   = (const float*)d_in[16];
  const float* Wr2   = (const float*)d_in[17];
  const float* br2   = (const float*)d_in[18];
  const float* We2   = (const float*)d_in[19];
  const float* att2  = (const float*)d_in[20];
  const float* bias2 = (const float*)d_in[21];
  const float* Wd1   = (const float*)d_in[22];
  const float* bd1   = (const float*)d_in[23];
  const float* Wd2   = (const float*)d_in[24];
  const float* bd2   = (const float*)d_in[25];

  const int* srcA = eidx;
  const int* dstA = eidx + NE;

  char* ws = (char*)d_ws;
  size_t off = 0;
  auto alloc = [&](size_t bytes) -> char* {
    char* p = ws + off;
    off += (bytes + 255) & ~(size_t)255;
    return p;
  };

  // zero region (deg, cursor, sum8) must stay first & contiguous
  int*   deg    = (int*)alloc(NN * 4);
  int*   cursor = (int*)alloc(NN * 4);
  float* sum8   = (float*)alloc(NN * 8 * 4);
  size_t zero_bytes = off;
  int*   rowptr = (int*)alloc((NN + 1) * 4);
  int*   csr    = (int*)alloc((size_t)(NE + NN) * 4);
  float* wl1e = (float*)alloc(4096 * 4);
  float* wr1e = (float*)alloc(4096 * 4);
  float* wfe1 = (float*)alloc(2048 * 4);
  float* wfe2 = (float*)alloc(512 * 4);
  float* bl1e = (float*)alloc(256 * 4);
  float* br1e = (float*)alloc(256 * 4);
  float* bfe1 = (float*)alloc(256 * 4);
  float* bfe2 = (float*)alloc(64 * 4);
  float* xl1  = (float*)alloc((size_t)NN * 256 * 4);
  float* xr1  = (float*)alloc((size_t)NN * 256 * 4);
  float* out1 = (float*)alloc((size_t)NN * 256 * 4);
  float* xl2  = (float*)alloc((size_t)NN * 64 * 4);
  float* xr2  = (float*)alloc((size_t)NN * 64 * 4);
  float* out2 = (float*)alloc((size_t)NN * 64 * 4);
  float* pooled = (float*)alloc((size_t)NB * 64 * 4);

  int zn = (int)(zero_bytes / 4);
  k_zero<<<(zn + 255) / 256, 256, 0, stream>>>((int*)d_ws, zn);
  k_fuse<<<(11584 + 255) / 256, 256, 0, stream>>>(Wn, bn, We, be, Wl1, bl1, Wr1, br1, We1, We2,
                                                  wl1e, bl1e, wr1e, br1e, wfe1, bfe1, wfe2, bfe2);
  k_deg<<<(NE + 255) / 256, 256, 0, stream>>>(dstA, eattr, deg, sum8);
  k_scan<<<1, 1024, 0, stream>>>(deg, rowptr);
  k_csr<<<(NE + NN + 255) / 256, 256, 0, stream>>>(dstA, rowptr, deg, cursor, csr);
  k_lin1<<<NN, 256, 0, stream>>>(x, wl1e, bl1e, wr1e, br1e, xl1, xr1);
  k_conv1<<<(NN + 3) / 4, 256, 0, stream>>>(srcA, eattr, rowptr, sum8, csr, xl1, xr1,
                                            att1, bias1, wfe1, bfe1, out1);
  k_lin2<<<(NN + 3) / 4, 256, 0, stream>>>(out1, Wl2, bl2, Wr2, br2, xl2, xr2);
  k_conv2<<<(NN + 3) / 4, 256, 0, stream>>>(srcA, eattr, rowptr, sum8, csr, xl2, xr2,
                                            att2, bias2, wfe2, bfe2, out2);
  k_pool<<<NB, 256, 0, stream>>>(batch, out2, pooled);
  k_dec<<<1, 1024, 0, stream>>>(pooled, Wd1, bd1, Wd2, bd2, (float*)d_out);
}

// Round 3
// 1006.865 us; speedup vs baseline: 1.5559x; 1.5559x over previous
//
#include <hip/hip_runtime.h>
#include <math.h>

#define NN 50000
#define NE 800000
#define NB 64

// XOR-permuted column layout (involution): storage[p] holds original column P(p).
__device__ __forceinline__ int permcol(int j) {
  return (((j >> 6) ^ (j & 3)) << 6) | (j & 63);
}

// ---------------- zero ----------------
__global__ void k_zero(int* __restrict__ p, int n) {
  int i = blockIdx.x * blockDim.x + threadIdx.x;
  if (i < n) p[i] = 0;
}

// ---------------- fused weight precompute (writes conv1-side tensors permuted) ----------------
__global__ void k_fuse(const float* __restrict__ Wn, const float* __restrict__ bn,
                       const float* __restrict__ We, const float* __restrict__ be,
                       const float* __restrict__ Wl1, const float* __restrict__ bl1,
                       const float* __restrict__ Wr1, const float* __restrict__ br1,
                       const float* __restrict__ We1, const float* __restrict__ We2,
                       const float* __restrict__ att1, const float* __restrict__ bias1,
                       float* __restrict__ wl1e, float* __restrict__ bl1e,
                       float* __restrict__ wr1e, float* __restrict__ br1e,
                       float* __restrict__ wfe1, float* __restrict__ bfe1,
                       float* __restrict__ wfe2, float* __restrict__ bfe2,
                       float* __restrict__ att1p, float* __restrict__ bias1p) {
  int t = blockIdx.x * blockDim.x + threadIdx.x;
  if (t < 4096) {
    int i = t >> 8, j = t & 255; float s = 0.f;
    for (int k = 0; k < 64; k++) s += Wn[i * 64 + k] * Wl1[k * 256 + j];
    wl1e[i * 256 + permcol(j)] = s;
  } else if (t < 8192) {
    int u = t - 4096; int i = u >> 8, j = u & 255; float s = 0.f;
    for (int k = 0; k < 64; k++) s += Wn[i * 64 + k] * Wr1[k * 256 + j];
    wr1e[i * 256 + permcol(j)] = s;
  } else if (t < 10240) {
    int u = t - 8192; int i = u >> 8, j = u & 255; float s = 0.f;
    for (int k = 0; k < 64; k++) s += We[i * 64 + k] * We1[k * 256 + j];
    wfe1[i * 256 + permcol(j)] = s;
  } else if (t < 10752) {
    int u = t - 10240; int i = u >> 6, j = u & 63; float s = 0.f;
    for (int k = 0; k < 64; k++) s += We[i * 64 + k] * We2[k * 64 + j];
    wfe2[u] = s;
  } else if (t < 11008) {
    int j = t - 10752; float s = bl1[j];
    for (int k = 0; k < 64; k++) s += bn[k] * Wl1[k * 256 + j];
    bl1e[permcol(j)] = s;
  } else if (t < 11264) {
    int j = t - 11008; float s = br1[j];
    for (int k = 0; k < 64; k++) s += bn[k] * Wr1[k * 256 + j];
    br1e[permcol(j)] = s;
  } else if (t < 11520) {
    int j = t - 11264; float s = 0.f;
    for (int k = 0; k < 64; k++) s += be[k] * We1[k * 256 + j];
    bfe1[permcol(j)] = s;
  } else if (t < 11584) {
    int j = t - 11520; float s = 0.f;
    for (int k = 0; k < 64; k++) s += be[k] * We2[k * 64 + j];
    bfe2[j] = s;
  } else if (t < 11840) {
    int j = t - 11584;
    att1p[permcol(j)] = att1[j];
  } else if (t < 12096) {
    int j = t - 11840;
    bias1p[permcol(j)] = bias1[j];
  }
}

// ---------------- degree only ----------------
__global__ void k_deg(const int* __restrict__ dstA, int* __restrict__ deg) {
  int e = blockIdx.x * blockDim.x + threadIdx.x;
  if (e < NE) atomicAdd(&deg[dstA[e]], 1);
}

// ---------------- 3-kernel scan of (deg+1) -> rowptr ----------------
__global__ __launch_bounds__(1024) void k_scan1(const int* __restrict__ deg,
                                                int* __restrict__ incl, int* __restrict__ partials) {
  __shared__ int sm[1024];
  int i = blockIdx.x * 1024 + threadIdx.x;
  int v = (i < NN) ? (deg[i] + 1) : 0;
  sm[threadIdx.x] = v;
  __syncthreads();
  for (int off = 1; off < 1024; off <<= 1) {
    int t = (threadIdx.x >= off) ? sm[threadIdx.x - off] : 0;
    __syncthreads();
    sm[threadIdx.x] += t;
    __syncthreads();
  }
  if (i < NN) incl[i] = sm[threadIdx.x];
  if (threadIdx.x == 1023) partials[blockIdx.x] = sm[1023];
}

__global__ void k_scan2(int* __restrict__ partials, int* __restrict__ rowptr, int nblk) {
  int t = threadIdx.x;
  int v = (t < nblk) ? partials[t] : 0;
  for (int off = 1; off < 64; off <<= 1) {
    int u = __shfl_up(v, off, 64);
    if (t >= off) v += u;
  }
  if (t < nblk) partials[t] = v;       // inclusive block sums
  if (t == nblk - 1) rowptr[NN] = v;   // total
}

__global__ void k_scan3(const int* __restrict__ deg, const int* __restrict__ incl,
                        const int* __restrict__ partials, int* __restrict__ rowptr) {
  int i = blockIdx.x * blockDim.x + threadIdx.x;
  if (i >= NN) return;
  int blk = i >> 10;
  int base = blk ? partials[blk - 1] : 0;
  rowptr[i] = base + incl[i] - (deg[i] + 1);
}

// ---------------- CSR fill: entry = (eid, src); self-loop (eid=-1) at row end ----------------
__global__ void k_csr(const int* __restrict__ srcA, const int* __restrict__ dstA,
                      const int* __restrict__ rowptr, const int* __restrict__ deg,
                      int* __restrict__ cursor, int2* __restrict__ csr) {
  int t = blockIdx.x * blockDim.x + threadIdx.x;
  if (t < NE) {
    int d = dstA[t];
    int pos = rowptr[d] + atomicAdd(&cursor[d], 1);
    csr[pos] = make_int2(t, srcA[t]);
  } else if (t < NE + NN) {
    int n = t - NE;
    csr[rowptr[n] + deg[n]] = make_int2(-1, n);
  }
}

// ---------------- lin1: xl1/xr1 (permuted layout) ; 4 nodes per block ----------------
__global__ __launch_bounds__(256) void k_lin1(const float* __restrict__ x,
                                              const float* __restrict__ wl, const float* __restrict__ bl,
                                              const float* __restrict__ wr, const float* __restrict__ br,
                                              float* __restrict__ xl, float* __restrict__ xr) {
  __shared__ float xs[4][16];
  int nb = blockIdx.x * 4;
  int t = threadIdx.x;
  if (t < 64) xs[t >> 4][t & 15] = x[nb * 16 + t];
  __syncthreads();
  float accl[4], accr[4];
  float blv = bl[t], brv = br[t];
#pragma unroll
  for (int u = 0; u < 4; u++) { accl[u] = blv; accr[u] = brv; }
#pragma unroll
  for (int k = 0; k < 16; k++) {
    float wlv = wl[k * 256 + t], wrv = wr[k * 256 + t];
#pragma unroll
    for (int u = 0; u < 4; u++) {
      accl[u] += xs[u][k] * wlv;
      accr[u] += xs[u][k] * wrv;
    }
  }
#pragma unroll
  for (int u = 0; u < 4; u++) {
    xl[(size_t)(nb + u) * 256 + t] = accl[u];
    xr[(size_t)(nb + u) * 256 + t] = accr[u];
  }
}

// ---------------- conv1: GATv2 4 heads, j-space (lane owns head lane&3) ----------------
__global__ __launch_bounds__(256) void k_conv1(
    const float* __restrict__ eattr,
    const int* __restrict__ rowptr,
    const int2* __restrict__ csr,
    const float* __restrict__ xl, const float* __restrict__ xrg,
    const float* __restrict__ att1p, const float* __restrict__ bias1p,
    const float* __restrict__ wfe1, const float* __restrict__ bfe1,
    float* __restrict__ out1) {
  int d = (blockIdx.x * blockDim.x + threadIdx.x) >> 6;
  int lane = threadIdx.x & 63;
  if (d >= NN) return;

  float xr_l[4], att_l[4], bfe_l[4], acc[4], wfe_l[4][8], eksum[8];
#pragma unroll
  for (int j = 0; j < 4; j++) {
    xr_l[j] = xrg[(size_t)d * 256 + j * 64 + lane];
    att_l[j] = att1p[j * 64 + lane];
    bfe_l[j] = bfe1[j * 64 + lane];
    acc[j] = 0.f;
#pragma unroll
    for (int k = 0; k < 8; k++) wfe_l[j][k] = wfe1[k * 256 + j * 64 + lane];
  }
#pragma unroll
  for (int k = 0; k < 8; k++) eksum[k] = 0.f;
  float mrun = -INFINITY, lrun = 0.f;  // owned-head state

  int beg = rowptr[d], end = rowptr[d + 1];
  float invdeg = 1.f / fmaxf((float)(end - beg - 1), 1.f);

  int2 ent = csr[beg];
  for (int idx = beg; idx < end; ++idx) {
    int2 nxt = csr[idx + 1];  // csr padded by 1 entry
    int eid = ent.x, s = ent.y;
    float ek[8];
    if (eid >= 0) {
      float4 a = *(const float4*)(eattr + (size_t)eid * 8);
      float4 b = *(const float4*)(eattr + (size_t)eid * 8 + 4);
      ek[0] = a.x; ek[1] = a.y; ek[2] = a.z; ek[3] = a.w;
      ek[4] = b.x; ek[5] = b.y; ek[6] = b.z; ek[7] = b.w;
#pragma unroll
      for (int k = 0; k < 8; k++) eksum[k] += ek[k];
    } else {
#pragma unroll
      for (int k = 0; k < 8; k++) ek[k] = eksum[k] * invdeg;
    }
    const float* xb = xl + (size_t)s * 256;
    float part[4], xls[4];
#pragma unroll
    for (int j = 0; j < 4; j++) {
      float ep = bfe_l[j];
#pragma unroll
      for (int k = 0; k < 8; k++) ep += ek[k] * wfe_l[j][k];
      float xs = xb[j * 64 + lane];
      xls[j] = xs;
      float m = xs + xr_l[j] + ep;
      m = (m > 0.f) ? m : 0.2f * m;
      part[j] = att_l[j] * m;
    }
    // j-space reduction: after xor1+xor2 steps, part[0] = owned head over 4-channel group
    float t0 = __shfl_xor(part[1], 1, 64);
    float t1 = __shfl_xor(part[0], 1, 64);
    float t2 = __shfl_xor(part[3], 1, 64);
    float t3 = __shfl_xor(part[2], 1, 64);
    part[0] += t0; part[1] += t1; part[2] += t2; part[3] += t3;
    t0 = __shfl_xor(part[2], 2, 64);
    t1 = __shfl_xor(part[3], 2, 64);
    t2 = __shfl_xor(part[0], 2, 64);
    t3 = __shfl_xor(part[1], 2, 64);
    part[0] += t0; part[1] += t1; part[2] += t2; part[3] += t3;
    float v = part[0];  // owned head, group partial
    v += __shfl_xor(v, 4, 64);
    v += __shfl_xor(v, 8, 64);
    v += __shfl_xor(v, 16, 64);
    v += __shfl_xor(v, 32, 64);  // full logit for head lane&3, in every lane

    if (__ballot(v > mrun)) {  // wave-uniform rescale (sc=1 where no new max)
      float nm = fmaxf(mrun, v);
      float sc = __expf(mrun - nm);
      mrun = nm;
      lrun *= sc;
      float sc1 = __shfl_xor(sc, 1, 64);
      float sc2 = __shfl_xor(sc, 2, 64);
      float sc3 = __shfl_xor(sc1, 2, 64);
      acc[0] *= sc; acc[1] *= sc1; acc[2] *= sc2; acc[3] *= sc3;
    }
    float p0 = __expf(v - mrun);
    lrun += p0;
    float p1 = __shfl_xor(p0, 1, 64);
    float p2 = __shfl_xor(p0, 2, 64);
    float p3 = __shfl_xor(p1, 2, 64);
    acc[0] += p0 * xls[0]; acc[1] += p1 * xls[1];
    acc[2] += p2 * xls[2]; acc[3] += p3 * xls[3];
    ent = nxt;
  }
  float lr0 = lrun;
  float lr1 = __shfl_xor(lr0, 1, 64);
  float lr2 = __shfl_xor(lr0, 2, 64);
  float lr3 = __shfl_xor(lr1, 2, 64);
  float lr[4] = {lr0, lr1, lr2, lr3};
#pragma unroll
  for (int j = 0; j < 4; j++) {
    float o = acc[j] / (lr[j] + 1e-16f) + bias1p[j * 64 + lane];
    out1[(size_t)d * 256 + j * 64 + lane] = (o > 0.f) ? o : (__expf(o) - 1.f);
  }
}

// ---------------- lin2: reads permuted out1, writes normal-layout xl2/xr2; 16 nodes/block ----------------
__global__ __launch_bounds__(256) void k_lin2(const float* __restrict__ in,
                                              const float* __restrict__ wl, const float* __restrict__ bl,
                                              const float* __restrict__ wr, const float* __restrict__ br,
                                              float* __restrict__ xl, float* __restrict__ xr) {
  int col = threadIdx.x & 63;
  int grp = threadIdx.x >> 6;
  int node0 = blockIdx.x * 16 + grp * 4;
  float sl[4], sr[4];
  float blv = bl[col], brv = br[col];
#pragma unroll
  for (int u = 0; u < 4; u++) { sl[u] = blv; sr[u] = brv; }
  const float4* r0 = (const float4*)(in + (size_t)(node0 + 0) * 256);
  const float4* r1 = (const float4*)(in + (size_t)(node0 + 1) * 256);
  const float4* r2 = (const float4*)(in + (size_t)(node0 + 2) * 256);
  const float4* r3 = (const float4*)(in + (size_t)(node0 + 3) * 256);
#pragma unroll 4
  for (int g4 = 0; g4 < 64; g4++) {
    int jj = g4 >> 4;
    int cc0 = (g4 & 15) << 2;
    int i0 = ((jj ^ 0) << 6) + cc0 + 0;
    int i1 = ((jj ^ 1) << 6) + cc0 + 1;
    int i2 = ((jj ^ 2) << 6) + cc0 + 2;
    int i3 = ((jj ^ 3) << 6) + cc0 + 3;
    float wl0 = wl[i0 * 64 + col], wl1v = wl[i1 * 64 + col];
    float wl2v = wl[i2 * 64 + col], wl3v = wl[i3 * 64 + col];
    float wr0 = wr[i0 * 64 + col], wr1v = wr[i1 * 64 + col];
    float wr2v = wr[i2 * 64 + col], wr3v = wr[i3 * 64 + col];
    float4 v0 = r0[g4], v1 = r1[g4], v2 = r2[g4], v3 = r3[g4];
    sl[0] += v0.x * wl0 + v0.y * wl1v + v0.z * wl2v + v0.w * wl3v;
    sl[1] += v1.x * wl0 + v1.y * wl1v + v1.z * wl2v + v1.w * wl3v;
    sl[2] += v2.x * wl0 + v2.y * wl1v + v2.z * wl2v + v2.w * wl3v;
    sl[3] += v3.x * wl0 + v3.y * wl1v + v3.z * wl2v + v3.w * wl3v;
    sr[0] += v0.x * wr0 + v0.y * wr1v + v0.z * wr2v + v0.w * wr3v;
    sr[1] += v1.x * wr0 + v1.y * wr1v + v1.z * wr2v + v1.w * wr3v;
    sr[2] += v2.x * wr0 + v2.y * wr1v + v2.z * wr2v + v2.w * wr3v;
    sr[3] += v3.x * wr0 + v3.y * wr1v + v3.z * wr2v + v3.w * wr3v;
  }
#pragma unroll
  for (int u = 0; u < 4; u++) {
    xl[(size_t)(node0 + u) * 64 + col] = sl[u];
    xr[(size_t)(node0 + u) * 64 + col] = sr[u];
  }
}

// ---------------- conv2: GATv2 1 head ----------------
__global__ __launch_bounds__(256) void k_conv2(
    const float* __restrict__ eattr,
    const int* __restrict__ rowptr,
    const int2* __restrict__ csr,
    const float* __restrict__ xl, const float* __restrict__ xrg,
    const float* __restrict__ att2, const float* __restrict__ bias2,
    const float* __restrict__ wfe2, const float* __restrict__ bfe2,
    float* __restrict__ out2) {
  int d = (blockIdx.x * blockDim.x + threadIdx.x) >> 6;
  int lane = threadIdx.x & 63;
  if (d >= NN) return;
  float xr_l = xrg[(size_t)d * 64 + lane];
  float att_l = att2[lane];
  float bfe_l = bfe2[lane];
  float wfe_l[8], eksum[8];
#pragma unroll
  for (int k = 0; k < 8; k++) { wfe_l[k] = wfe2[k * 64 + lane]; eksum[k] = 0.f; }
  float acc = 0.f, mrun = -INFINITY, lrun = 0.f;
  int beg = rowptr[d], end = rowptr[d + 1];
  float invdeg = 1.f / fmaxf((float)(end - beg - 1), 1.f);
  int2 ent = csr[beg];
  for (int idx = beg; idx < end; ++idx) {
    int2 nxt = csr[idx + 1];
    int eid = ent.x, s = ent.y;
    float ek[8];
    if (eid >= 0) {
      float4 a = *(const float4*)(eattr + (size_t)eid * 8);
      float4 b = *(const float4*)(eattr + (size_t)eid * 8 + 4);
      ek[0] = a.x; ek[1] = a.y; ek[2] = a.z; ek[3] = a.w;
      ek[4] = b.x; ek[5] = b.y; ek[6] = b.z; ek[7] = b.w;
#pragma unroll
      for (int k = 0; k < 8; k++) eksum[k] += ek[k];
    } else {
#pragma unroll
      for (int k = 0; k < 8; k++) ek[k] = eksum[k] * invdeg;
    }
    float ep = bfe_l;
#pragma unroll
    for (int k = 0; k < 8; k++) ep += ek[k] * wfe_l[k];
    float xs = xl[(size_t)s * 64 + lane];
    float m = xs + xr_l + ep;
    m = (m > 0.f) ? m : 0.2f * m;
    float v = att_l * m;
    v += __shfl_xor(v, 1, 64);
    v += __shfl_xor(v, 2, 64);
    v += __shfl_xor(v, 4, 64);
    v += __shfl_xor(v, 8, 64);
    v += __shfl_xor(v, 16, 64);
    v += __shfl_xor(v, 32, 64);  // uniform
    if (v > mrun) {              // wave-uniform branch
      float sc = __expf(mrun - v);
      mrun = v;
      lrun *= sc;
      acc *= sc;
    }
    float p = __expf(v - mrun);
    lrun += p;
    acc += p * xs;
    ent = nxt;
  }
  out2[(size_t)d * 64 + lane] = acc / (lrun + 1e-16f) + bias2[lane];
}

// ---------------- global mean pool ----------------
__device__ __forceinline__ int lowerb(const int* a, int n, int v) {
  int lo = 0, hi = n;
  while (lo < hi) {
    int mid = (lo + hi) >> 1;
    if (a[mid] < v) lo = mid + 1; else hi = mid;
  }
  return lo;
}

__global__ __launch_bounds__(256) void k_pool(const int* __restrict__ batch,
                                              const float* __restrict__ out2,
                                              float* __restrict__ pooled) {
  int b = blockIdx.x;
  int start = lowerb(batch, NN, b);
  int end = lowerb(batch, NN, b + 1);
  int c = threadIdx.x & 63, sub = threadIdx.x >> 6;
  float s = 0.f;
  for (int i = start + sub; i < end; i += 4) s += out2[(size_t)i * 64 + c];
  __shared__ float sm[256];
  sm[threadIdx.x] = s;
  __syncthreads();
  if (sub == 0) {
    float tot = sm[c] + sm[64 + c] + sm[128 + c] + sm[192 + c];
    float cnt = fmaxf((float)(end - start), 1.f);
    pooled[b * 64 + c] = tot / cnt;
  }
}

// ---------------- decoder ----------------
__global__ __launch_bounds__(1024) void k_dec(const float* __restrict__ pooled,
                                              const float* __restrict__ Wd1, const float* __restrict__ bd1,
                                              const float* __restrict__ Wd2, const float* __restrict__ bd2,
                                              float* __restrict__ out) {
  __shared__ float hid[64 * 64];
  int t = threadIdx.x;
  for (int i = t; i < 4096; i += 1024) {
    int b = i >> 6, j = i & 63;
    float s = bd1[j];
#pragma unroll 8
    for (int k = 0; k < 64; k++) s += pooled[b * 64 + k] * Wd1[k * 64 + j];
    hid[i] = fmaxf(s, 0.f);
  }
  __syncthreads();
  if (t < 128) {
    int b = t >> 1, o = t & 1;
    float s = bd2[o];
#pragma unroll 8
    for (int k = 0; k < 64; k++) s += hid[b * 64 + k] * Wd2[k * 2 + o];
    out[t] = 1.f / (1.f + __expf(-s));
  }
}

extern "C" void kernel_launch(void* const* d_in, const int* in_sizes, int n_in,
                              void* d_out, int out_size, void* d_ws, size_t ws_size,
                              hipStream_t stream) {
  const float* x     = (const float*)d_in[0];
  const int*   eidx  = (const int*)d_in[1];
  const float* eattr = (const float*)d_in[2];
  const int*   batch = (const int*)d_in[3];
  const float* Wn    = (const float*)d_in[4];
  const float* bn    = (const float*)d_in[5];
  const float* We    = (const float*)d_in[6];
  const float* be    = (const float*)d_in[7];
  const float* Wl1   = (const float*)d_in[8];
  const float* bl1   = (const float*)d_in[9];
  const float* Wr1   = (const float*)d_in[10];
  const float* br1   = (const float*)d_in[11];
  const float* We1   = (const float*)d_in[12];
  const float* att1  = (const float*)d_in[13];
  const float* bias1 = (const float*)d_in[14];
  const float* Wl2   = (const float*)d_in[15];
  const float* bl2   = (const float*)d_in[16];
  const float* Wr2   = (const float*)d_in[17];
  const float* br2   = (const float*)d_in[18];
  const float* We2   = (const float*)d_in[19];
  const float* att2  = (const float*)d_in[20];
  const float* bias2 = (const float*)d_in[21];
  const float* Wd1   = (const float*)d_in[22];
  const float* bd1   = (const float*)d_in[23];
  const float* Wd2   = (const float*)d_in[24];
  const float* bd2   = (const float*)d_in[25];

  const int* srcA = eidx;
  const int* dstA = eidx + NE;

  char* ws = (char*)d_ws;
  size_t off = 0;
  auto alloc = [&](size_t bytes) -> char* {
    char* p = ws + off;
    off += (bytes + 255) & ~(size_t)255;
    return p;
  };

  // zero region (deg, cursor) must stay first & contiguous
  int*   deg    = (int*)alloc(NN * 4);
  int*   cursor = (int*)alloc(NN * 4);
  size_t zero_bytes = off;
  int*   rowptr   = (int*)alloc((NN + 1) * 4);
  int*   incl     = (int*)alloc(NN * 4);
  int*   partials = (int*)alloc(64 * 4);
  int2*  csr      = (int2*)alloc((size_t)(NE + NN + 1) * 8);
  float* wl1e  = (float*)alloc(4096 * 4);
  float* wr1e  = (float*)alloc(4096 * 4);
  float* wfe1  = (float*)alloc(2048 * 4);
  float* wfe2  = (float*)alloc(512 * 4);
  float* bl1e  = (float*)alloc(256 * 4);
  float* br1e  = (float*)alloc(256 * 4);
  float* bfe1  = (float*)alloc(256 * 4);
  float* bfe2  = (float*)alloc(64 * 4);
  float* att1p = (float*)alloc(256 * 4);
  float* bias1p= (float*)alloc(256 * 4);
  float* xl1   = (float*)alloc((size_t)NN * 256 * 4);
  float* xr1   = (float*)alloc((size_t)NN * 256 * 4);
  float* out1  = (float*)alloc((size_t)NN * 256 * 4);
  float* xl2   = (float*)alloc((size_t)NN * 64 * 4);
  float* xr2   = (float*)alloc((size_t)NN * 64 * 4);
  float* out2  = (float*)alloc((size_t)NN * 64 * 4);
  float* pooled = (float*)alloc((size_t)NB * 64 * 4);

  int zn = (int)(zero_bytes / 4);
  int nscan = (NN + 1023) / 1024;  // 49
  k_zero<<<(zn + 255) / 256, 256, 0, stream>>>((int*)d_ws, zn);
  k_fuse<<<(12096 + 255) / 256, 256, 0, stream>>>(Wn, bn, We, be, Wl1, bl1, Wr1, br1, We1, We2,
                                                  att1, bias1,
                                                  wl1e, bl1e, wr1e, br1e, wfe1, bfe1, wfe2, bfe2,
                                                  att1p, bias1p);
  k_deg<<<(NE + 255) / 256, 256, 0, stream>>>(dstA, deg);
  k_scan1<<<nscan, 1024, 0, stream>>>(deg, incl, partials);
  k_scan2<<<1, 64, 0, stream>>>(partials, rowptr, nscan);
  k_scan3<<<(NN + 255) / 256, 256, 0, stream>>>(deg, incl, partials, rowptr);
  k_csr<<<(NE + NN + 255) / 256, 256, 0, stream>>>(srcA, dstA, rowptr, deg, cursor, csr);
  k_lin1<<<NN / 4, 256, 0, stream>>>(x, wl1e, bl1e, wr1e, br1e, xl1, xr1);
  k_conv1<<<(NN + 3) / 4, 256, 0, stream>>>(eattr, rowptr, csr, xl1, xr1,
                                            att1p, bias1p, wfe1, bfe1, out1);
  k_lin2<<<NN / 16, 256, 0, stream>>>(out1, Wl2, bl2, Wr2, br2, xl2, xr2);
  k_conv2<<<(NN + 3) / 4, 256, 0, stream>>>(eattr, rowptr, csr, xl2, xr2,
                                            att2, bias2, wfe2, bfe2, out2);
  k_pool<<<NB, 256, 0, stream>>>(batch, out2, pooled);
  k_dec<<<1, 1024, 0, stream>>>(pooled, Wd1, bd1, Wd2, bd2, (float*)d_out);
}

// Round 4
// 771.381 us; speedup vs baseline: 2.0308x; 1.3053x over previous
//
#include <hip/hip_runtime.h>
#include <math.h>

#define NN 50000
#define NE 800000
#define NB 64

// Lane-major position layout for conv1-space vectors (256 cols):
// original col c = head*64 + chan  ->  pos = chan*4 + (head ^ (chan&3))
// Lane l holds pos l*4 .. l*4+3, i.e. slot j = head (j ^ (l&3)) at channel l.
__device__ __forceinline__ int permpos(int c) {
  return ((c & 63) << 2) | (((c >> 6) ^ c) & 3);
}

// ---------------- zero ----------------
__global__ void k_zero(int* __restrict__ p, int n) {
  int i = blockIdx.x * blockDim.x + threadIdx.x;
  if (i < n) p[i] = 0;
}

// ---------------- fused weight precompute (conv1-side tensors in permpos layout) ----------------
__global__ void k_fuse(const float* __restrict__ Wn, const float* __restrict__ bn,
                       const float* __restrict__ We, const float* __restrict__ be,
                       const float* __restrict__ Wl1, const float* __restrict__ bl1,
                       const float* __restrict__ Wr1, const float* __restrict__ br1,
                       const float* __restrict__ We1, const float* __restrict__ We2,
                       const float* __restrict__ att1, const float* __restrict__ bias1,
                       float* __restrict__ wl1e, float* __restrict__ bl1e,
                       float* __restrict__ wr1e, float* __restrict__ br1e,
                       float* __restrict__ wfe1, float* __restrict__ bfe1,
                       float* __restrict__ wfe2, float* __restrict__ bfe2,
                       float* __restrict__ att1p, float* __restrict__ bias1p) {
  int t = blockIdx.x * blockDim.x + threadIdx.x;
  if (t < 4096) {
    int i = t >> 8, j = t & 255; float s = 0.f;
    for (int k = 0; k < 64; k++) s += Wn[i * 64 + k] * Wl1[k * 256 + j];
    wl1e[i * 256 + permpos(j)] = s;
  } else if (t < 8192) {
    int u = t - 4096; int i = u >> 8, j = u & 255; float s = 0.f;
    for (int k = 0; k < 64; k++) s += Wn[i * 64 + k] * Wr1[k * 256 + j];
    wr1e[i * 256 + permpos(j)] = s;
  } else if (t < 10240) {
    int u = t - 8192; int i = u >> 8, j = u & 255; float s = 0.f;
    for (int k = 0; k < 64; k++) s += We[i * 64 + k] * We1[k * 256 + j];
    wfe1[i * 256 + permpos(j)] = s;
  } else if (t < 10752) {
    int u = t - 10240; int i = u >> 6, j = u & 63; float s = 0.f;
    for (int k = 0; k < 64; k++) s += We[i * 64 + k] * We2[k * 64 + j];
    wfe2[u] = s;
  } else if (t < 11008) {
    int j = t - 10752; float s = bl1[j];
    for (int k = 0; k < 64; k++) s += bn[k] * Wl1[k * 256 + j];
    bl1e[permpos(j)] = s;
  } else if (t < 11264) {
    int j = t - 11008; float s = br1[j];
    for (int k = 0; k < 64; k++) s += bn[k] * Wr1[k * 256 + j];
    br1e[permpos(j)] = s;
  } else if (t < 11520) {
    int j = t - 11264; float s = 0.f;
    for (int k = 0; k < 64; k++) s += be[k] * We1[k * 256 + j];
    bfe1[permpos(j)] = s;
  } else if (t < 11584) {
    int j = t - 11520; float s = 0.f;
    for (int k = 0; k < 64; k++) s += be[k] * We2[k * 64 + j];
    bfe2[j] = s;
  } else if (t < 11840) {
    int j = t - 11584;
    att1p[permpos(j)] = att1[j];
  } else if (t < 12096) {
    int j = t - 11840;
    bias1p[permpos(j)] = bias1[j];
  }
}

// ---------------- degree only ----------------
__global__ void k_deg(const int* __restrict__ dstA, int* __restrict__ deg) {
  int e = blockIdx.x * blockDim.x + threadIdx.x;
  if (e < NE) atomicAdd(&deg[dstA[e]], 1);
}

// ---------------- 3-kernel scan of (deg+1) -> rowptr ----------------
__global__ __launch_bounds__(1024) void k_scan1(const int* __restrict__ deg,
                                                int* __restrict__ incl, int* __restrict__ partials) {
  __shared__ int sm[1024];
  int i = blockIdx.x * 1024 + threadIdx.x;
  int v = (i < NN) ? (deg[i] + 1) : 0;
  sm[threadIdx.x] = v;
  __syncthreads();
  for (int off = 1; off < 1024; off <<= 1) {
    int t = (threadIdx.x >= off) ? sm[threadIdx.x - off] : 0;
    __syncthreads();
    sm[threadIdx.x] += t;
    __syncthreads();
  }
  if (i < NN) incl[i] = sm[threadIdx.x];
  if (threadIdx.x == 1023) partials[blockIdx.x] = sm[1023];
}

__global__ void k_scan2(int* __restrict__ partials, int* __restrict__ rowptr, int nblk) {
  int t = threadIdx.x;
  int v = (t < nblk) ? partials[t] : 0;
  for (int off = 1; off < 64; off <<= 1) {
    int u = __shfl_up(v, off, 64);
    if (t >= off) v += u;
  }
  if (t < nblk) partials[t] = v;
  if (t == nblk - 1) rowptr[NN] = v;
}

__global__ void k_scan3(const int* __restrict__ deg, const int* __restrict__ incl,
                        const int* __restrict__ partials, int* __restrict__ rowptr) {
  int i = blockIdx.x * blockDim.x + threadIdx.x;
  if (i >= NN) return;
  int blk = i >> 10;
  int base = blk ? partials[blk - 1] : 0;
  rowptr[i] = base + incl[i] - (deg[i] + 1);
}

// ---------------- CSR fill: entry=(eid,src); self-loop eid=NE+n at row end ----------------
__global__ void k_csr(const int* __restrict__ srcA, const int* __restrict__ dstA,
                      const int* __restrict__ rowptr, const int* __restrict__ deg,
                      int* __restrict__ cursor, int2* __restrict__ csr) {
  int t = blockIdx.x * blockDim.x + threadIdx.x;
  if (t < NE) {
    int d = dstA[t];
    int pos = rowptr[d] + atomicAdd(&cursor[d], 1);
    csr[pos] = make_int2(t, srcA[t]);
  } else if (t < NE + NN) {
    int n = t - NE;
    csr[rowptr[n] + deg[n]] = make_int2(NE + n, n);
  }
}

// ---------------- per-node mean edge_attr (self-loop fill) : one wave per node ----------------
__global__ __launch_bounds__(256) void k_loop8(const int* __restrict__ rowptr,
                                               const int2* __restrict__ csr,
                                               const float* __restrict__ eattr,
                                               float* __restrict__ lattr) {
  int d = (blockIdx.x * blockDim.x + threadIdx.x) >> 6;
  int lane = threadIdx.x & 63;
  if (d >= NN) return;
  int beg = rowptr[d], endReal = rowptr[d + 1] - 1;  // last entry is the self-loop
  int k = lane & 7, sub = lane >> 3;
  float s = 0.f;
  for (int i = beg + sub; i < endReal; i += 8) {
    int eid = csr[i].x;
    s += eattr[(size_t)eid * 8 + k];
  }
  s += __shfl_xor(s, 8, 64);
  s += __shfl_xor(s, 16, 64);
  s += __shfl_xor(s, 32, 64);
  float invdeg = 1.f / fmaxf((float)(endReal - beg), 1.f);
  if (lane < 8) lattr[(size_t)d * 8 + lane] = s * invdeg;
}

// ---------------- lin1: xl1/xr1 (permpos layout, weights pre-permuted) ----------------
__global__ __launch_bounds__(256) void k_lin1(const float* __restrict__ x,
                                              const float* __restrict__ wl, const float* __restrict__ bl,
                                              const float* __restrict__ wr, const float* __restrict__ br,
                                              float* __restrict__ xl, float* __restrict__ xr) {
  __shared__ float xs[4][16];
  int nb = blockIdx.x * 4;
  int t = threadIdx.x;
  if (t < 64) xs[t >> 4][t & 15] = x[nb * 16 + t];
  __syncthreads();
  float accl[4], accr[4];
  float blv = bl[t], brv = br[t];
#pragma unroll
  for (int u = 0; u < 4; u++) { accl[u] = blv; accr[u] = brv; }
#pragma unroll
  for (int k = 0; k < 16; k++) {
    float wlv = wl[k * 256 + t], wrv = wr[k * 256 + t];
#pragma unroll
    for (int u = 0; u < 4; u++) {
      accl[u] += xs[u][k] * wlv;
      accr[u] += xs[u][k] * wrv;
    }
  }
#pragma unroll
  for (int u = 0; u < 4; u++) {
    xl[(size_t)(nb + u) * 256 + t] = accl[u];
    xr[(size_t)(nb + u) * 256 + t] = accr[u];
  }
}

// edge-attr fetch (uniform eid; self-loops come from lattr)
__device__ __forceinline__ void load_ek(const float* __restrict__ eattr,
                                        const float* __restrict__ lattr,
                                        int eid, float ek[8]) {
  const float* b; int ei;
  if (eid < NE) { b = eattr; ei = eid; } else { b = lattr; ei = eid - NE; }
  const float* p = b + (size_t)ei * 8;
#pragma unroll
  for (int k = 0; k < 8; k++) ek[k] = p[k];
}

// j-space logit reduction: part[j] holds head (j^(lane&3)) @ channel lane.
// Returns full logit of head (lane&3) in every lane. 7 shuffles.
__device__ __forceinline__ float jreduce(float part[4]) {
  part[0] += __shfl_xor(part[1], 1, 64);
  part[2] += __shfl_xor(part[3], 1, 64);
  float v = part[0] + __shfl_xor(part[2], 2, 64);
  v += __shfl_xor(v, 4, 64);
  v += __shfl_xor(v, 8, 64);
  v += __shfl_xor(v, 16, 64);
  v += __shfl_xor(v, 32, 64);
  return v;
}

// ---------------- conv1: GATv2 4 heads, groups of 4 edges ----------------
__global__ __launch_bounds__(256) void k_conv1(
    const float* __restrict__ eattr, const float* __restrict__ lattr,
    const int* __restrict__ rowptr, const int2* __restrict__ csr,
    const float* __restrict__ xl, const float* __restrict__ xrg,
    const float* __restrict__ att1p, const float* __restrict__ bias1p,
    const float* __restrict__ wfe1, const float* __restrict__ bfe1,
    float* __restrict__ out1) {
  int d = __builtin_amdgcn_readfirstlane((blockIdx.x * blockDim.x + threadIdx.x) >> 6);
  int lane = threadIdx.x & 63;
  if (d >= NN) return;
  int l4 = lane << 2;
  float4 xr4 = *(const float4*)(xrg + (size_t)d * 256 + l4);
  float4 at4 = *(const float4*)(att1p + l4);
  float4 bf4 = *(const float4*)(bfe1 + l4);
  float4 wf[8];
#pragma unroll
  for (int k = 0; k < 8; k++) wf[k] = *(const float4*)(wfe1 + k * 256 + l4);

  float acc0 = 0.f, acc1 = 0.f, acc2 = 0.f, acc3 = 0.f;
  float mrun = -INFINITY, lrun = 0.f;
  int beg = rowptr[d], end = rowptr[d + 1];

  // part for one edge given its eid and gathered xl row
  auto epart = [&](int eid, const float4& x4, float part[4]) {
    float ek[8];
    load_ek(eattr, lattr, eid, ek);
    float e0 = bf4.x, e1 = bf4.y, e2 = bf4.z, e3 = bf4.w;
#pragma unroll
    for (int k = 0; k < 8; k++) {
      e0 += ek[k] * wf[k].x;
      e1 += ek[k] * wf[k].y;
      e2 += ek[k] * wf[k].z;
      e3 += ek[k] * wf[k].w;
    }
    float m0 = x4.x + xr4.x + e0; m0 = (m0 > 0.f) ? m0 : 0.2f * m0;
    float m1 = x4.y + xr4.y + e1; m1 = (m1 > 0.f) ? m1 : 0.2f * m1;
    float m2 = x4.z + xr4.z + e2; m2 = (m2 > 0.f) ? m2 : 0.2f * m2;
    float m3 = x4.w + xr4.w + e3; m3 = (m3 > 0.f) ? m3 : 0.2f * m3;
    part[0] = at4.x * m0; part[1] = at4.y * m1;
    part[2] = at4.z * m2; part[3] = at4.w * m3;
  };

  int idx = beg;
  for (; idx + 4 <= end; idx += 4) {
    int2 e0 = csr[idx], e1 = csr[idx + 1], e2 = csr[idx + 2], e3 = csr[idx + 3];
    float4 x0 = *(const float4*)(xl + (size_t)e0.y * 256 + l4);
    float4 x1 = *(const float4*)(xl + (size_t)e1.y * 256 + l4);
    float4 x2 = *(const float4*)(xl + (size_t)e2.y * 256 + l4);
    float4 x3 = *(const float4*)(xl + (size_t)e3.y * 256 + l4);
    float pa[4], pb[4], pc[4], pd[4];
    epart(e0.x, x0, pa); epart(e1.x, x1, pb);
    epart(e2.x, x2, pc); epart(e3.x, x3, pd);
    float v0 = jreduce(pa), v1 = jreduce(pb), v2 = jreduce(pc), v3 = jreduce(pd);
    float gmax = fmaxf(fmaxf(v0, v1), fmaxf(v2, v3));
    if (__ballot(gmax > mrun)) {
      float nm = fmaxf(mrun, gmax);
      float sc = __expf(mrun - nm);
      mrun = nm; lrun *= sc;
      float sc1 = __shfl_xor(sc, 1, 64);
      float sc2 = __shfl_xor(sc, 2, 64);
      float sc3 = __shfl_xor(sc1, 2, 64);
      acc0 *= sc; acc1 *= sc1; acc2 *= sc2; acc3 *= sc3;
    }
    float q0 = __expf(v0 - mrun), q1 = __expf(v1 - mrun);
    float q2 = __expf(v2 - mrun), q3 = __expf(v3 - mrun);
    lrun += q0 + q1 + q2 + q3;
    {
      float a1 = __shfl_xor(q0, 1, 64), a2 = __shfl_xor(q0, 2, 64), a3 = __shfl_xor(a1, 2, 64);
      acc0 += q0 * x0.x; acc1 += a1 * x0.y; acc2 += a2 * x0.z; acc3 += a3 * x0.w;
    }
    {
      float a1 = __shfl_xor(q1, 1, 64), a2 = __shfl_xor(q1, 2, 64), a3 = __shfl_xor(a1, 2, 64);
      acc0 += q1 * x1.x; acc1 += a1 * x1.y; acc2 += a2 * x1.z; acc3 += a3 * x1.w;
    }
    {
      float a1 = __shfl_xor(q2, 1, 64), a2 = __shfl_xor(q2, 2, 64), a3 = __shfl_xor(a1, 2, 64);
      acc0 += q2 * x2.x; acc1 += a1 * x2.y; acc2 += a2 * x2.z; acc3 += a3 * x2.w;
    }
    {
      float a1 = __shfl_xor(q3, 1, 64), a2 = __shfl_xor(q3, 2, 64), a3 = __shfl_xor(a1, 2, 64);
      acc0 += q3 * x3.x; acc1 += a1 * x3.y; acc2 += a2 * x3.z; acc3 += a3 * x3.w;
    }
  }
  for (; idx < end; ++idx) {
    int2 e0 = csr[idx];
    float4 x0 = *(const float4*)(xl + (size_t)e0.y * 256 + l4);
    float pa[4];
    epart(e0.x, x0, pa);
    float v0 = jreduce(pa);
    if (__ballot(v0 > mrun)) {
      float nm = fmaxf(mrun, v0);
      float sc = __expf(mrun - nm);
      mrun = nm; lrun *= sc;
      float sc1 = __shfl_xor(sc, 1, 64);
      float sc2 = __shfl_xor(sc, 2, 64);
      float sc3 = __shfl_xor(sc1, 2, 64);
      acc0 *= sc; acc1 *= sc1; acc2 *= sc2; acc3 *= sc3;
    }
    float q0 = __expf(v0 - mrun);
    lrun += q0;
    float a1 = __shfl_xor(q0, 1, 64), a2 = __shfl_xor(q0, 2, 64), a3 = __shfl_xor(a1, 2, 64);
    acc0 += q0 * x0.x; acc1 += a1 * x0.y; acc2 += a2 * x0.z; acc3 += a3 * x0.w;
  }

  float lr0 = lrun;
  float lr1 = __shfl_xor(lr0, 1, 64);
  float lr2 = __shfl_xor(lr0, 2, 64);
  float lr3 = __shfl_xor(lr1, 2, 64);
  float4 bi4 = *(const float4*)(bias1p + l4);
  float4 o;
  o.x = acc0 / (lr0 + 1e-16f) + bi4.x;
  o.y = acc1 / (lr1 + 1e-16f) + bi4.y;
  o.z = acc2 / (lr2 + 1e-16f) + bi4.z;
  o.w = acc3 / (lr3 + 1e-16f) + bi4.w;
  o.x = (o.x > 0.f) ? o.x : (__expf(o.x) - 1.f);
  o.y = (o.y > 0.f) ? o.y : (__expf(o.y) - 1.f);
  o.z = (o.z > 0.f) ? o.z : (__expf(o.z) - 1.f);
  o.w = (o.w > 0.f) ? o.w : (__expf(o.w) - 1.f);
  *(float4*)(out1 + (size_t)d * 256 + l4) = o;
}

// ---------------- lin2: reads permpos out1, writes normal xl2/xr2; 16 nodes/block ----------------
__global__ __launch_bounds__(256) void k_lin2(const float* __restrict__ in,
                                              const float* __restrict__ wl, const float* __restrict__ bl,
                                              const float* __restrict__ wr, const float* __restrict__ br,
                                              float* __restrict__ xl, float* __restrict__ xr) {
  int col = threadIdx.x & 63;
  int grp = threadIdx.x >> 6;
  int node0 = blockIdx.x * 16 + grp * 4;
  float sl[4], sr[4];
  float blv = bl[col], brv = br[col];
#pragma unroll
  for (int u = 0; u < 4; u++) { sl[u] = blv; sr[u] = brv; }
  const float4* r0 = (const float4*)(in + (size_t)(node0 + 0) * 256);
  const float4* r1 = (const float4*)(in + (size_t)(node0 + 1) * 256);
  const float4* r2 = (const float4*)(in + (size_t)(node0 + 2) * 256);
  const float4* r3 = (const float4*)(in + (size_t)(node0 + 3) * 256);
#pragma unroll 4
  for (int g4 = 0; g4 < 64; g4++) {
    // pos 4*g4+j  <->  orig col ((j ^ (g4&3)) << 6) + g4
    int b = g4 & 3;
    int i0 = ((0 ^ b) << 6) + g4;
    int i1 = ((1 ^ b) << 6) + g4;
    int i2 = ((2 ^ b) << 6) + g4;
    int i3 = ((3 ^ b) << 6) + g4;
    float wl0 = wl[i0 * 64 + col], wl1v = wl[i1 * 64 + col];
    float wl2v = wl[i2 * 64 + col], wl3v = wl[i3 * 64 + col];
    float wr0 = wr[i0 * 64 + col], wr1v = wr[i1 * 64 + col];
    float wr2v = wr[i2 * 64 + col], wr3v = wr[i3 * 64 + col];
    float4 v0 = r0[g4], v1 = r1[g4], v2 = r2[g4], v3 = r3[g4];
    sl[0] += v0.x * wl0 + v0.y * wl1v + v0.z * wl2v + v0.w * wl3v;
    sl[1] += v1.x * wl0 + v1.y * wl1v + v1.z * wl2v + v1.w * wl3v;
    sl[2] += v2.x * wl0 + v2.y * wl1v + v2.z * wl2v + v2.w * wl3v;
    sl[3] += v3.x * wl0 + v3.y * wl1v + v3.z * wl2v + v3.w * wl3v;
    sr[0] += v0.x * wr0 + v0.y * wr1v + v0.z * wr2v + v0.w * wr3v;
    sr[1] += v1.x * wr0 + v1.y * wr1v + v1.z * wr2v + v1.w * wr3v;
    sr[2] += v2.x * wr0 + v2.y * wr1v + v2.z * wr2v + v2.w * wr3v;
    sr[3] += v3.x * wr0 + v3.y * wr1v + v3.z * wr2v + v3.w * wr3v;
  }
#pragma unroll
  for (int u = 0; u < 4; u++) {
    xl[(size_t)(node0 + u) * 64 + col] = sl[u];
    xr[(size_t)(node0 + u) * 64 + col] = sr[u];
  }
}

// ---------------- conv2: GATv2 1 head, groups of 4 edges ----------------
__global__ __launch_bounds__(256) void k_conv2(
    const float* __restrict__ eattr, const float* __restrict__ lattr,
    const int* __restrict__ rowptr, const int2* __restrict__ csr,
    const float* __restrict__ xl, const float* __restrict__ xrg,
    const float* __restrict__ att2, const float* __restrict__ bias2,
    const float* __restrict__ wfe2, const float* __restrict__ bfe2,
    float* __restrict__ out2) {
  int d = __builtin_amdgcn_readfirstlane((blockIdx.x * blockDim.x + threadIdx.x) >> 6);
  int lane = threadIdx.x & 63;
  if (d >= NN) return;
  float xr_l = xrg[(size_t)d * 64 + lane];
  float att_l = att2[lane];
  float bfe_l = bfe2[lane];
  float wfe_l[8];
#pragma unroll
  for (int k = 0; k < 8; k++) wfe_l[k] = wfe2[k * 64 + lane];
  float acc = 0.f, mrun = -INFINITY, lrun = 0.f;
  int beg = rowptr[d], end = rowptr[d + 1];

  auto elogit = [&](int eid, float xs) {
    float ek[8];
    load_ek(eattr, lattr, eid, ek);
    float ep = bfe_l;
#pragma unroll
    for (int k = 0; k < 8; k++) ep += ek[k] * wfe_l[k];
    float m = xs + xr_l + ep;
    m = (m > 0.f) ? m : 0.2f * m;
    float v = att_l * m;
    v += __shfl_xor(v, 1, 64);
    v += __shfl_xor(v, 2, 64);
    v += __shfl_xor(v, 4, 64);
    v += __shfl_xor(v, 8, 64);
    v += __shfl_xor(v, 16, 64);
    v += __shfl_xor(v, 32, 64);
    return v;  // uniform across lanes
  };

  int idx = beg;
  for (; idx + 4 <= end; idx += 4) {
    int2 e0 = csr[idx], e1 = csr[idx + 1], e2 = csr[idx + 2], e3 = csr[idx + 3];
    float x0 = xl[(size_t)e0.y * 64 + lane];
    float x1 = xl[(size_t)e1.y * 64 + lane];
    float x2 = xl[(size_t)e2.y * 64 + lane];
    float x3 = xl[(size_t)e3.y * 64 + lane];
    float v0 = elogit(e0.x, x0), v1 = elogit(e1.x, x1);
    float v2 = elogit(e2.x, x2), v3 = elogit(e3.x, x3);
    float gmax = fmaxf(fmaxf(v0, v1), fmaxf(v2, v3));
    if (gmax > mrun) {  // uniform branch
      float sc = __expf(mrun - gmax);
      mrun = gmax; lrun *= sc; acc *= sc;
    }
    float q0 = __expf(v0 - mrun), q1 = __expf(v1 - mrun);
    float q2 = __expf(v2 - mrun), q3 = __expf(v3 - mrun);
    lrun += q0 + q1 + q2 + q3;
    acc += q0 * x0 + q1 * x1 + q2 * x2 + q3 * x3;
  }
  for (; idx < end; ++idx) {
    int2 e0 = csr[idx];
    float x0 = xl[(size_t)e0.y * 64 + lane];
    float v0 = elogit(e0.x, x0);
    if (v0 > mrun) {
      float sc = __expf(mrun - v0);
      mrun = v0; lrun *= sc; acc *= sc;
    }
    float q0 = __expf(v0 - mrun);
    lrun += q0;
    acc += q0 * x0;
  }
  out2[(size_t)d * 64 + lane] = acc / (lrun + 1e-16f) + bias2[lane];
}

// ---------------- global mean pool ----------------
__device__ __forceinline__ int lowerb(const int* a, int n, int v) {
  int lo = 0, hi = n;
  while (lo < hi) {
    int mid = (lo + hi) >> 1;
    if (a[mid] < v) lo = mid + 1; else hi = mid;
  }
  return lo;
}

__global__ __launch_bounds__(256) void k_pool(const int* __restrict__ batch,
                                              const float* __restrict__ out2,
                                              float* __restrict__ pooled) {
  int b = blockIdx.x;
  int start = lowerb(batch, NN, b);
  int end = lowerb(batch, NN, b + 1);
  int c = threadIdx.x & 63, sub = threadIdx.x >> 6;
  float s = 0.f;
  for (int i = start + sub; i < end; i += 4) s += out2[(size_t)i * 64 + c];
  __shared__ float sm[256];
  sm[threadIdx.x] = s;
  __syncthreads();
  if (sub == 0) {
    float tot = sm[c] + sm[64 + c] + sm[128 + c] + sm[192 + c];
    float cnt = fmaxf((float)(end - start), 1.f);
    pooled[b * 64 + c] = tot / cnt;
  }
}

// ---------------- decoder ----------------
__global__ __launch_bounds__(1024) void k_dec(const float* __restrict__ pooled,
                                              const float* __restrict__ Wd1, const float* __restrict__ bd1,
                                              const float* __restrict__ Wd2, const float* __restrict__ bd2,
                                              float* __restrict__ out) {
  __shared__ float hid[64 * 64];
  int t = threadIdx.x;
  for (int i = t; i < 4096; i += 1024) {
    int b = i >> 6, j = i & 63;
    float s = bd1[j];
#pragma unroll 8
    for (int k = 0; k < 64; k++) s += pooled[b * 64 + k] * Wd1[k * 64 + j];
    hid[i] = fmaxf(s, 0.f);
  }
  __syncthreads();
  if (t < 128) {
    int b = t >> 1, o = t & 1;
    float s = bd2[o];
#pragma unroll 8
    for (int k = 0; k < 64; k++) s += hid[b * 64 + k] * Wd2[k * 2 + o];
    out[t] = 1.f / (1.f + __expf(-s));
  }
}

extern "C" void kernel_launch(void* const* d_in, const int* in_sizes, int n_in,
                              void* d_out, int out_size, void* d_ws, size_t ws_size,
                              hipStream_t stream) {
  const float* x     = (const float*)d_in[0];
  const int*   eidx  = (const int*)d_in[1];
  const float* eattr = (const float*)d_in[2];
  const int*   batch = (const int*)d_in[3];
  const float* Wn    = (const float*)d_in[4];
  const float* bn    = (const float*)d_in[5];
  const float* We    = (const float*)d_in[6];
  const float* be    = (const float*)d_in[7];
  const float* Wl1   = (const float*)d_in[8];
  const float* bl1   = (const float*)d_in[9];
  const float* Wr1   = (const float*)d_in[10];
  const float* br1   = (const float*)d_in[11];
  const float* We1   = (const float*)d_in[12];
  const float* att1  = (const float*)d_in[13];
  const float* bias1 = (const float*)d_in[14];
  const float* Wl2   = (const float*)d_in[15];
  const float* bl2   = (const float*)d_in[16];
  const float* Wr2   = (const float*)d_in[17];
  const float* br2   = (const float*)d_in[18];
  const float* We2   = (const float*)d_in[19];
  const float* att2  = (const float*)d_in[20];
  const float* bias2 = (const float*)d_in[21];
  const float* Wd1   = (const float*)d_in[22];
  const float* bd1   = (const float*)d_in[23];
  const float* Wd2   = (const float*)d_in[24];
  const float* bd2   = (const float*)d_in[25];

  const int* srcA = eidx;
  const int* dstA = eidx + NE;

  char* ws = (char*)d_ws;
  size_t off = 0;
  auto alloc = [&](size_t bytes) -> char* {
    char* p = ws + off;
    off += (bytes + 255) & ~(size_t)255;
    return p;
  };

  // zero region (deg, cursor) must stay first & contiguous
  int*   deg    = (int*)alloc(NN * 4);
  int*   cursor = (int*)alloc(NN * 4);
  size_t zero_bytes = off;
  int*   rowptr   = (int*)alloc((NN + 1) * 4);
  int*   incl     = (int*)alloc(NN * 4);
  int*   partials = (int*)alloc(64 * 4);
  int2*  csr      = (int2*)alloc((size_t)(NE + NN + 1) * 8);
  float* lattr = (float*)alloc((size_t)NN * 8 * 4);
  float* wl1e  = (float*)alloc(4096 * 4);
  float* wr1e  = (float*)alloc(4096 * 4);
  float* wfe1  = (float*)alloc(2048 * 4);
  float* wfe2  = (float*)alloc(512 * 4);
  float* bl1e  = (float*)alloc(256 * 4);
  float* br1e  = (float*)alloc(256 * 4);
  float* bfe1  = (float*)alloc(256 * 4);
  float* bfe2  = (float*)alloc(64 * 4);
  float* att1p = (float*)alloc(256 * 4);
  float* bias1p= (float*)alloc(256 * 4);
  float* xl1   = (float*)alloc((size_t)NN * 256 * 4);
  float* xr1   = (float*)alloc((size_t)NN * 256 * 4);
  float* out1  = (float*)alloc((size_t)NN * 256 * 4);
  float* xl2   = (float*)alloc((size_t)NN * 64 * 4);
  float* xr2   = (float*)alloc((size_t)NN * 64 * 4);
  float* out2  = (float*)alloc((size_t)NN * 64 * 4);
  float* pooled = (float*)alloc((size_t)NB * 64 * 4);

  int zn = (int)(zero_bytes / 4);
  int nscan = (NN + 1023) / 1024;  // 49
  k_zero<<<(zn + 255) / 256, 256, 0, stream>>>((int*)d_ws, zn);
  k_fuse<<<(12096 + 255) / 256, 256, 0, stream>>>(Wn, bn, We, be, Wl1, bl1, Wr1, br1, We1, We2,
                                                  att1, bias1,
                                                  wl1e, bl1e, wr1e, br1e, wfe1, bfe1, wfe2, bfe2,
                                                  att1p, bias1p);
  k_deg<<<(NE + 255) / 256, 256, 0, stream>>>(dstA, deg);
  k_scan1<<<nscan, 1024, 0, stream>>>(deg, incl, partials);
  k_scan2<<<1, 64, 0, stream>>>(partials, rowptr, nscan);
  k_scan3<<<(NN + 255) / 256, 256, 0, stream>>>(deg, incl, partials, rowptr);
  k_csr<<<(NE + NN + 255) / 256, 256, 0, stream>>>(srcA, dstA, rowptr, deg, cursor, csr);
  k_loop8<<<(NN + 3) / 4, 256, 0, stream>>>(rowptr, csr, eattr, lattr);
  k_lin1<<<NN / 4, 256, 0, stream>>>(x, wl1e, bl1e, wr1e, br1e, xl1, xr1);
  k_conv1<<<(NN + 3) / 4, 256, 0, stream>>>(eattr, lattr, rowptr, csr, xl1, xr1,
                                            att1p, bias1p, wfe1, bfe1, out1);
  k_lin2<<<NN / 16, 256, 0, stream>>>(out1, Wl2, bl2, Wr2, br2, xl2, xr2);
  k_conv2<<<(NN + 3) / 4, 256, 0, stream>>>(eattr, lattr, rowptr, csr, xl2, xr2,
                                            att2, bias2, wfe2, bfe2, out2);
  k_pool<<<NB, 256, 0, stream>>>(batch, out2, pooled);
  k_dec<<<1, 1024, 0, stream>>>(pooled, Wd1, bd1, Wd2, bd2, (float*)d_out);
}